// Round 2
// baseline (363.317 us; speedup 1.0000x reference)
//
#include <hip/hip_runtime.h>
#include <math.h>

// Problem constants (from reference setup_inputs)
#define BB 16
#define FF 256
#define TT 8192
#define KK 204   // int(256 * (1 - 0.2)) = 204 kept per row

typedef float v4 __attribute__((ext_vector_type(4)));

// ---------------------------------------------------------------------------
// Kernel 1 (tiny, 16 blocks): compute the (B,F) keep flags ONCE.
// Mask semantics (exact, matches reference): v = sigmoid(w[f]) + noise[b,f]*0.05;
//   keep iff #{j : v_j > v_f} < K  (== x2 >= kth-largest, tie-inclusive);
//   straight-through binary == (kept && v_f > 0) ? 1.0 : 0.0.
// binary_mask[b,0,0,f] IS the flag value, so flags are written directly into
// the t=0 row of the binary_mask output region — no workspace, L2-hot readback.
// ---------------------------------------------------------------------------
__global__ void __launch_bounds__(256) mask_kernel(const float* __restrict__ w,
                                                   const float* __restrict__ noise,
                                                   float* __restrict__ mask0) {
    __shared__ float vals[FF];
    const int b = blockIdx.x;
    const int f = threadIdx.x;
    const float v = 1.0f / (1.0f + expf(-w[f])) + noise[b * FF + f] * 0.05f;
    vals[f] = v;
    __syncthreads();
    int cnt = 0;
    const v4* __restrict__ vp = (const v4*)vals;
#pragma unroll 8
    for (int j = 0; j < FF / 4; ++j) {      // vectorized rank loop, 64 iters
        const v4 q = vp[j];
        cnt += (q.x > v) + (q.y > v) + (q.z > v) + (q.w > v);
    }
    mask0[(size_t)b * (TT * FF) + f] = (cnt < KK && v > 0.0f) ? 1.0f : 0.0f;
}

// ---------------------------------------------------------------------------
// Kernel 2 (6144 blocks x 256): PURE streaming. A/B vs round 1: ALL
// nontemporal hints removed — plain cached loads/stores, same as the 6.4 TB/s
// rocclr fill. Everything else identical.
//   blocks [0,4096):    masked_x — block = one (b,f) row of 8192 floats.
//                       Uniform flag load; kept rows: 8x float4 copy;
//                       dropped rows: zero stores, NO x read.
//   blocks [4096,6144): binary_mask — 128 blocks per b, 64 t-rows each;
//                       wave reads its 1KB flag row (L2-hot) and replicates.
// ---------------------------------------------------------------------------
__global__ void __launch_bounds__(256) stream_kernel(const v4* __restrict__ x4,
                                                     const float* __restrict__ mask0,
                                                     v4* __restrict__ out4) {
    const int bid = blockIdx.x;
    const int tid = threadIdx.x;

    if (bid < BB * FF) {
        // ---- masked_x: row bid = b*256+f, 2048 float4 ----
        const int b = bid >> 8;
        const int f = bid & 255;
        const float flag = mask0[(size_t)b * (TT * FF) + f];  // block-uniform

        const v4* __restrict__ src = x4 + ((size_t)bid << 11);
        v4* __restrict__ dst = out4 + ((size_t)bid << 11);

        if (flag != 0.0f) {   // block-uniform branch
            v4 xv[8];
#pragma unroll
            for (int u = 0; u < 8; ++u)
                xv[u] = src[tid + (u << 8)];
#pragma unroll
            for (int u = 0; u < 8; ++u)
                dst[tid + (u << 8)] = xv[u];
        } else {
            const v4 z = {0.0f, 0.0f, 0.0f, 0.0f};
#pragma unroll
            for (int u = 0; u < 8; ++u)
                dst[tid + (u << 8)] = z;
        }
    } else {
        // ---- binary_mask: (B,1,T,F); 128 blocks per b, 64 t-rows each ----
        const int q = bid - BB * FF;        // 0..2047
        const int b = q >> 7;
        const int tchunk = q & 127;         // 64 t-rows per block
        const int lane = tid & 63;
        const int wid = tid >> 6;           // 4 waves

        // 1KB flag row for this b, L2/L3-hot (written by mask_kernel)
        const v4 mv = ((const v4*)(mask0 + (size_t)b * (TT * FF)))[lane];

        v4* __restrict__ dst = out4 + (size_t)(BB * FF * TT / 4)
                             + ((size_t)(b * TT + (tchunk << 6)) << 6);
#pragma unroll
        for (int t = 0; t < 64; t += 4)
            dst[((size_t)(t + wid) << 6) | lane] = mv;
    }
}

extern "C" void kernel_launch(void* const* d_in, const int* in_sizes, int n_in,
                              void* d_out, int out_size, void* d_ws, size_t ws_size,
                              hipStream_t stream) {
    const float* x     = (const float*)d_in[0];   // (16,1,256,8192)
    const float* w     = (const float*)d_in[1];   // (1,1,1,256)
    const float* noise = (const float*)d_in[2];   // (16,1,1,256)

    (void)out_size; (void)ws_size; (void)d_ws; (void)n_in; (void)in_sizes;

    // binary_mask region starts at float offset B*F*T inside d_out;
    // its t=0 rows double as the flag store.
    float* mask0 = (float*)d_out + (size_t)BB * FF * TT;

    mask_kernel<<<BB, 256, 0, stream>>>(w, noise, mask0);
    stream_kernel<<<BB * FF + 2048, 256, 0, stream>>>(
        (const v4*)x, mask0, (v4*)d_out);
}

// Round 3
// 352.733 us; speedup vs baseline: 1.0300x; 1.0300x over previous
//
#include <hip/hip_runtime.h>
#include <math.h>

// Problem constants (from reference setup_inputs)
#define BB 16
#define FF 256
#define TT 8192
#define KK 204   // int(256 * (1 - 0.2)) = 204 kept per row

typedef float v4 __attribute__((ext_vector_type(4)));

// ---------------------------------------------------------------------------
// Kernel 1 (tiny, 16 blocks): compute the (B,F) keep flags ONCE.
// Mask semantics (exact, matches reference): v = sigmoid(w[f]) + noise[b,f]*0.05;
//   keep iff #{j : v_j > v_f} < K  (== x2 >= kth-largest, tie-inclusive);
//   straight-through binary == (kept && v_f > 0) ? 1.0 : 0.0.
// binary_mask[b,0,0,f] IS the flag value, so flags are written directly into
// the t=0 row of the binary_mask output region — no workspace, L2-hot readback.
// ---------------------------------------------------------------------------
__global__ void __launch_bounds__(256) mask_kernel(const float* __restrict__ w,
                                                   const float* __restrict__ noise,
                                                   float* __restrict__ mask0) {
    __shared__ float vals[FF];
    const int b = blockIdx.x;
    const int f = threadIdx.x;
    const float v = 1.0f / (1.0f + expf(-w[f])) + noise[b * FF + f] * 0.05f;
    vals[f] = v;
    __syncthreads();
    int cnt = 0;
    const v4* __restrict__ vp = (const v4*)vals;
#pragma unroll 8
    for (int j = 0; j < FF / 4; ++j) {      // vectorized rank loop, 64 iters
        const v4 q = vp[j];
        cnt += (q.x > v) + (q.y > v) + (q.z > v) + (q.w > v);
    }
    mask0[(size_t)b * (TT * FF) + f] = (cnt < KK && v > 0.0f) ? 1.0f : 0.0f;
}

// ---------------------------------------------------------------------------
// Kernel 2 (6144 blocks x 256): PURE streaming, NT hints RESTORED (round-2 A/B
// showed removing them cost ~10 us on the 268 MB write stream).
//   blocks [0,4096):    masked_x — block = one (b,f) row of 8192 floats.
//                       Uniform flag load; kept rows: NT 8x float4 copy;
//                       dropped rows: NT zero stores, NO x read.
//   blocks [4096,6144): binary_mask — 128 blocks per b, 64 t-rows each;
//                       wave reads its 1KB flag row (L2-hot) and replicates.
// ---------------------------------------------------------------------------
__global__ void __launch_bounds__(256) stream_kernel(const v4* __restrict__ x4,
                                                     const float* __restrict__ mask0,
                                                     v4* __restrict__ out4) {
    const int bid = blockIdx.x;
    const int tid = threadIdx.x;

    if (bid < BB * FF) {
        // ---- masked_x: row bid = b*256+f, 2048 float4 ----
        const int b = bid >> 8;
        const int f = bid & 255;
        const float flag = mask0[(size_t)b * (TT * FF) + f];  // block-uniform

        const v4* __restrict__ src = x4 + ((size_t)bid << 11);
        v4* __restrict__ dst = out4 + ((size_t)bid << 11);

        if (flag != 0.0f) {   // block-uniform branch
            v4 xv[8];
#pragma unroll
            for (int u = 0; u < 8; ++u)
                xv[u] = __builtin_nontemporal_load(&src[tid + (u << 8)]);
#pragma unroll
            for (int u = 0; u < 8; ++u)
                __builtin_nontemporal_store(xv[u], &dst[tid + (u << 8)]);
        } else {
            const v4 z = {0.0f, 0.0f, 0.0f, 0.0f};
#pragma unroll
            for (int u = 0; u < 8; ++u)
                __builtin_nontemporal_store(z, &dst[tid + (u << 8)]);
        }
    } else {
        // ---- binary_mask: (B,1,T,F); 128 blocks per b, 64 t-rows each ----
        const int q = bid - BB * FF;        // 0..2047
        const int b = q >> 7;
        const int tchunk = q & 127;         // 64 t-rows per block
        const int lane = tid & 63;
        const int wid = tid >> 6;           // 4 waves

        // 1KB flag row for this b, L2/L3-hot (written by mask_kernel)
        const v4 mv = ((const v4*)(mask0 + (size_t)b * (TT * FF)))[lane];

        v4* __restrict__ dst = out4 + (size_t)(BB * FF * TT / 4)
                             + ((size_t)(b * TT + (tchunk << 6)) << 6);
#pragma unroll
        for (int t = 0; t < 64; t += 4)
            __builtin_nontemporal_store(mv, &dst[((size_t)(t + wid) << 6) | lane]);
    }
}

extern "C" void kernel_launch(void* const* d_in, const int* in_sizes, int n_in,
                              void* d_out, int out_size, void* d_ws, size_t ws_size,
                              hipStream_t stream) {
    const float* x     = (const float*)d_in[0];   // (16,1,256,8192)
    const float* w     = (const float*)d_in[1];   // (1,1,1,256)
    const float* noise = (const float*)d_in[2];   // (16,1,1,256)

    (void)out_size; (void)ws_size; (void)d_ws; (void)n_in; (void)in_sizes;

    // binary_mask region starts at float offset B*F*T inside d_out;
    // its t=0 rows double as the flag store.
    float* mask0 = (float*)d_out + (size_t)BB * FF * TT;

    mask_kernel<<<BB, 256, 0, stream>>>(w, noise, mask0);
    stream_kernel<<<BB * FF + 2048, 256, 0, stream>>>(
        (const v4*)x, mask0, (v4*)d_out);
}